// Round 3
// baseline (674.978 us; speedup 1.0000x reference)
//
#include <hip/hip_runtime.h>
#include <math.h>

#define L 256
#define CZ 128
#define NH 4
#define HD 32
#define P (L*L)            // 65536
#define NTOT (CZ*P)        // 8388608
#define EPSV 1e-5f
#define SCALE 0.17677669529663687f   // 1/sqrt(32)

typedef unsigned short u16;

__device__ __forceinline__ float bu2f(u16 u){ return __uint_as_float(((unsigned)u) << 16); }
__device__ __forceinline__ u16 f2bu(float x){
  unsigned u = __float_as_uint(x);
  return (u16)((u + 0x7fffu + ((u >> 16) & 1u)) >> 16);   // RNE
}

// generic input load / output store, FP32 chooses fp32 vs bf16(u16)
template<bool FP32>
__device__ __forceinline__ float ldin(const void* p, size_t i){
  return FP32 ? ((const float*)p)[i] : bu2f(((const u16*)p)[i]);
}
template<bool FP32>
__device__ __forceinline__ void stout(void* p, size_t i, float v){
  if (FP32) ((float*)p)[i] = v; else ((u16*)p)[i] = f2bu(v);
}

// ---- workspace layout (float offsets); total 344848 floats = 1.38 MB ----
// ws[0], ws[1]: LN sum / sumsq.  ((int*)ws)[2]: dtype flag (1 = fp32 inputs)
#define OFF_WQT   16
#define OFF_WKT   (OFF_WQT+16384)
#define OFF_WVT   (OFF_WKT+16384)
#define OFF_WGT   (OFF_WVT+16384)
#define OFF_WREPT (OFF_WGT+16384)
#define OFF_WBT   (OFF_WREPT+16384)   // 512 floats [cin][h]
#define OFF_BGF   (OFF_WBT+512)       // 128
#define OFF_BREPF (OFF_BGF+128)       // 128
#define OFF_BIAS  (OFF_BREPF+128)     // NH*P floats, layout T[h][b][a] = map[h][a][b]

#define GUARD(ws) if (((((const volatile int*)(ws))[2]) != 0) != FP32) return;

// ---- k-1: dtype detect. bf16 view of fp32 data contains huge/NaN values. ----
__global__ __launch_bounds__(256) void detect_dtype(const void* pair, int* flag){
  int t = threadIdx.x;
  const u16* u = (const u16*)pair;
  int big = 0;
  for (int k = t; k < 2048; k += 256){
    float av = fabsf(bu2f(u[k]));
    if (!(av < 1e4f)) big = 1;      // catches huge and NaN
  }
  __shared__ int sb[256];
  sb[t] = big; __syncthreads();
  for (int off = 128; off > 0; off >>= 1){
    if (t < off) sb[t] |= sb[t+off];
    __syncthreads();
  }
  if (t == 0) flag[2] = sb[0];
}

// ---- k0: transpose + fp32-convert weights ----
template<bool FP32>
__global__ __launch_bounds__(256) void prep_w(const void* wq, const void* wk,
    const void* wv, const void* wg, const void* wrep, const void* wb,
    const void* bg, const void* brep, float* ws){
  GUARD(ws);
  int idx = blockIdx.x*256 + threadIdx.x;      // 16384
  int oc = idx >> 7, cin = idx & 127;
  int t = cin*128 + oc;
  ws[OFF_WQT  + t] = ldin<FP32>(wq, idx);
  ws[OFF_WKT  + t] = ldin<FP32>(wk, idx);
  ws[OFF_WVT  + t] = ldin<FP32>(wv, idx);
  ws[OFF_WGT  + t] = ldin<FP32>(wg, idx);
  ws[OFF_WREPT+ t] = ldin<FP32>(wrep, idx);
  if (idx < 512){ int h = idx >> 7, ci = idx & 127; ws[OFF_WBT + ci*4 + h] = ldin<FP32>(wb, idx); }
  if (idx < 128){ ws[OFF_BGF + idx] = ldin<FP32>(bg, idx); ws[OFF_BREPF + idx] = ldin<FP32>(brep, idx); }
}

// ---- k1: global mean / sum-of-squares ----
template<bool FP32>
__global__ __launch_bounds__(256) void ln_reduce(const void* __restrict__ pair, float* ws){
  GUARD(ws);
  int t = threadIdx.x;
  int g = blockIdx.x*256 + t;                  // 256 blocks
  float s = 0.f, ss = 0.f;
  for (int u = 0; u < 128; ++u){
    float v = ldin<FP32>(pair, (size_t)u*65536 + g);
    s += v; ss += v*v;
  }
  __shared__ float sa[256], sb[256];
  sa[t] = s; sb[t] = ss;
  __syncthreads();
  for (int off = 128; off > 0; off >>= 1){
    if (t < off){ sa[t] += sa[t+off]; sb[t] += sb[t+off]; }
    __syncthreads();
  }
  if (t == 0){ atomicAdd(&ws[0], sa[0]); atomicAdd(&ws[1], sb[0]); }
}

// ---- k2: bias map, stored transposed T[h][b][a] = map[h][a][b] ----
template<bool FP32>
__global__ __launch_bounds__(256) void bias_kernel(const void* __restrict__ pair,
    const void* __restrict__ gamma, const void* __restrict__ beta, float* __restrict__ ws){
  GUARD(ws);
  int a = blockIdx.x, b = threadIdx.x;
  float mu   = ws[0] * (1.0f/NTOT);
  float var  = ws[1] * (1.0f/NTOT) - mu*mu;
  float rstd = rsqrtf(var + EPSV);
  float a0=0.f, a1=0.f, a2=0.f, a3=0.f;
  for (int c = 0; c < CZ; ++c){
    size_t idx = (size_t)c*P + (size_t)a*L + b;
    float xv = (ldin<FP32>(pair,idx) - mu)*rstd*ldin<FP32>(gamma,idx) + ldin<FP32>(beta,idx);
    const float* w4 = ws + OFF_WBT + c*4;      // wave-uniform
    a0 = fmaf(w4[0], xv, a0); a1 = fmaf(w4[1], xv, a1);
    a2 = fmaf(w4[2], xv, a2); a3 = fmaf(w4[3], xv, a3);
  }
  ws[OFF_BIAS + 0*P + b*L + a] = a0;
  ws[OFF_BIAS + 1*P + b*L + a] = a1;
  ws[OFF_BIAS + 2*P + b*L + a] = a2;
  ws[OFF_BIAS + 3*P + b*L + a] = a3;
}

// ---- k3: fused attention per (h,i). q,g,K,V computed in-block; O -> d_out ----
template<bool FP32>
__global__ __launch_bounds__(256) void attn_kernel(const void* __restrict__ pair,
    const void* __restrict__ gamma, const void* __restrict__ beta,
    float* __restrict__ ws, void* __restrict__ outp){
  GUARD(ws);
  __shared__ float sm[16384];                  // 64 KB union: xrow(bf16) then K|V(f32)
  u16* xr = (u16*)sm;
  int h = blockIdx.x >> 8, i = blockIdx.x & 255;
  int j = threadIdx.x;
  float mu   = ws[0] * (1.0f/NTOT);
  float var  = ws[1] * (1.0f/NTOT) - mu*mu;
  float rstd = rsqrtf(var + EPSV);
  for (int u = 0; u < 128; ++u){
    int lin = u*256 + j;
    int c = lin >> 8, jj = lin & 255;
    size_t idx = (size_t)c*P + (size_t)i*L + jj;
    xr[c*256 + jj] = f2bu((ldin<FP32>(pair,idx) - mu)*rstd*ldin<FP32>(gamma,idx) + ldin<FP32>(beta,idx));
  }
  __syncthreads();
  // per-thread column j of row i: q, g, k, v (head h)
  float q[HD], g[HD], kj[HD], vj[HD];
  #pragma unroll
  for (int o = 0; o < HD; ++o){ q[o]=0.f; g[o]=0.f; kj[o]=0.f; vj[o]=0.f; }
  for (int cin = 0; cin < CZ; ++cin){
    float xv = bu2f(xr[cin*256 + j]);
    const float* wq_ = ws + OFF_WQT + cin*128 + h*32;   // wave-uniform rows
    #pragma unroll
    for (int o = 0; o < HD; ++o) q[o]  = fmaf(wq_[o], xv, q[o]);
  }
  for (int cin = 0; cin < CZ; ++cin){
    float xv = bu2f(xr[cin*256 + j]);
    const float* wg_ = ws + OFF_WGT + cin*128 + h*32;
    #pragma unroll
    for (int o = 0; o < HD; ++o) g[o]  = fmaf(wg_[o], xv, g[o]);
  }
  for (int cin = 0; cin < CZ; ++cin){
    float xv = bu2f(xr[cin*256 + j]);
    const float* wk_ = ws + OFF_WKT + cin*128 + h*32;
    #pragma unroll
    for (int o = 0; o < HD; ++o) kj[o] = fmaf(wk_[o], xv, kj[o]);
  }
  for (int cin = 0; cin < CZ; ++cin){
    float xv = bu2f(xr[cin*256 + j]);
    const float* wv_ = ws + OFF_WVT + cin*128 + h*32;
    #pragma unroll
    for (int o = 0; o < HD; ++o) vj[o] = fmaf(wv_[o], xv, vj[o]);
  }
  __syncthreads();                             // all xr reads complete
  float* K = sm;                               // [256][32] f32
  float* V = sm + 8192;
  #pragma unroll
  for (int o = 0; o < HD; ++o){ K[j*HD + o] = kj[o]; V[j*HD + o] = vj[o]; }
  __syncthreads();
  #pragma unroll
  for (int o = 0; o < HD; ++o){
    float z = g[o] + ws[OFF_BGF + h*32 + o];
    g[o] = 1.0f / (1.0f + __expf(-z));
  }
  const float* brow = ws + OFF_BIAS + (size_t)h*P + j;
  float o_[HD];
  #pragma unroll
  for (int c = 0; c < HD; ++c) o_[c] = 0.f;
  float l = 0.f;
  for (int kk = 0; kk < L; ++kk){
    const float* kr = K + kk*HD;               // broadcast LDS read
    float s0=0.f, s1=0.f, s2=0.f, s3=0.f;
    #pragma unroll
    for (int c = 0; c < HD; c += 4){
      s0 = fmaf(q[c],   kr[c],   s0);
      s1 = fmaf(q[c+1], kr[c+1], s1);
      s2 = fmaf(q[c+2], kr[c+2], s2);
      s3 = fmaf(q[c+3], kr[c+3], s3);
    }
    float s = (s0+s1)+(s2+s3);
    s = fmaf(s, SCALE, brow[(size_t)kk*L]);    // + map[h][j][kk]
    float e = __expf(s);
    l += e;
    const float* vr = V + kk*HD;
    #pragma unroll
    for (int c = 0; c < HD; ++c) o_[c] = fmaf(e, vr[c], o_[c]);
  }
  float inv = 1.0f / l;
  #pragma unroll
  for (int c = 0; c < HD; ++c){                // channel m = c*NH + h
    stout<FP32>(outp, (size_t)(c*NH + h)*P + (size_t)i*L + j, o_[c]*inv*g[c]);
  }
}

// ---- k4: output projection, block-local staged RMW on d_out ----
template<bool FP32>
__global__ __launch_bounds__(256) void out_proj(float* __restrict__ ws, void* __restrict__ outp){
  GUARD(ws);
  __shared__ float gos[CZ*65];                 // +1 pad
  int blk = blockIdx.x;                        // 1024
  int i = blk >> 2, jb = (blk & 3) << 6;
  int t = threadIdx.x;
  for (int u = 0; u < 32; ++u){
    int lin = u*256 + t;
    int m = lin >> 6, p = lin & 63;
    gos[m*65 + p] = ldin<FP32>(outp, (size_t)m*P + (size_t)i*L + jb + p);
  }
  __syncthreads();                             // all reads staged before any write
  int p = t & 63, w4 = t >> 6;
  int woc = w4*32;
  float acc[32];
  #pragma unroll
  for (int o = 0; o < 32; ++o) acc[o] = 0.f;
  for (int cin = 0; cin < CZ; ++cin){
    float xv = gos[cin*65 + p];
    const float* wrow = ws + OFF_WREPT + cin*128 + woc;  // wave-uniform
    #pragma unroll
    for (int o = 0; o < 32; ++o) acc[o] = fmaf(wrow[o], xv, acc[o]);
  }
  #pragma unroll
  for (int o = 0; o < 32; ++o){
    int oc = woc + o;
    stout<FP32>(outp, (size_t)oc*P + (size_t)i*L + jb + p, acc[o] + ws[OFF_BREPF + oc]);
  }
}

extern "C" void kernel_launch(void* const* d_in, const int* in_sizes, int n_in,
                              void* d_out, int out_size, void* d_ws, size_t ws_size,
                              hipStream_t stream) {
  (void)in_sizes; (void)n_in; (void)out_size; (void)ws_size;
  const void* pair  = d_in[0];
  const void* gamma = d_in[1];
  const void* beta  = d_in[2];
  const void* wq    = d_in[3];
  const void* wk    = d_in[4];
  const void* wv    = d_in[5];
  const void* wb    = d_in[6];
  const void* wg    = d_in[7];
  const void* bg    = d_in[8];
  const void* wrep  = d_in[9];
  const void* brep  = d_in[10];
  float* ws = (float*)d_ws;

  hipMemsetAsync(d_ws, 0, 16, stream);         // zero stats + flag
  detect_dtype<<<1, 256, 0, stream>>>(pair, (int*)d_ws);

  prep_w<false>     <<<64,   256, 0, stream>>>(wq, wk, wv, wg, wrep, wb, bg, brep, ws);
  prep_w<true>      <<<64,   256, 0, stream>>>(wq, wk, wv, wg, wrep, wb, bg, brep, ws);
  ln_reduce<false>  <<<256,  256, 0, stream>>>(pair, ws);
  ln_reduce<true>   <<<256,  256, 0, stream>>>(pair, ws);
  bias_kernel<false><<<256,  256, 0, stream>>>(pair, gamma, beta, ws);
  bias_kernel<true> <<<256,  256, 0, stream>>>(pair, gamma, beta, ws);
  attn_kernel<false><<<1024, 256, 0, stream>>>(pair, gamma, beta, ws, d_out);
  attn_kernel<true> <<<1024, 256, 0, stream>>>(pair, gamma, beta, ws, d_out);
  out_proj<false>   <<<1024, 256, 0, stream>>>(ws, d_out);
  out_proj<true>    <<<1024, 256, 0, stream>>>(ws, d_out);
}